// Round 1
// baseline (484.970 us; speedup 1.0000x reference)
//
#include <hip/hip_runtime.h>

#define N_NODES  100000
#define N_EDGES  1200000
#define N_GRAPHS 1024
// HIDDEN = 64, IN_DIM = 4, OUT_DIM = 2

// ---------------- degree ----------------
__global__ void k_init_deg(float* __restrict__ deg) {
  int i = blockIdx.x * 256 + threadIdx.x;
  if (i < N_NODES) deg[i] = 1.0f;   // self-loop contributes 1 to every node
}

__global__ void k_deg(const int* __restrict__ ei, float* __restrict__ deg) {
  int e = blockIdx.x * 256 + threadIdx.x;
  if (e < N_EDGES) atomicAdd(&deg[ei[N_EDGES + e]], 1.0f);  // dst row
}

// ------- fused encoder + BN + h@W_gcn + self-loop init of agg -------
__global__ void k_enc(const float* __restrict__ x,
                      const float* __restrict__ Wenc, const float* __restrict__ benc,
                      const float* __restrict__ gamma, const float* __restrict__ beta,
                      const float* __restrict__ mean,  const float* __restrict__ var,
                      const float* __restrict__ Wgcn,
                      const float* __restrict__ deg,
                      float* __restrict__ hw, float* __restrict__ agg,
                      float* __restrict__ dis) {
  __shared__ float wLDS[64 * 64];
  __shared__ float hLDS[256];
  int tid = threadIdx.x;
  for (int i = tid; i < 64 * 64; i += 256) wLDS[i] = Wgcn[i];
  int lane = tid & 63;
  int grp  = tid >> 6;
  int node = blockIdx.x * 4 + grp;
  float hbn = 0.f;
  if (node < N_NODES) {
    float x0 = x[node * 4 + 0], x1 = x[node * 4 + 1];
    float x2 = x[node * 4 + 2], x3 = x[node * 4 + 3];
    float h = benc[lane] + x0 * Wenc[lane] + x1 * Wenc[64 + lane]
                         + x2 * Wenc[128 + lane] + x3 * Wenc[192 + lane];
    h = fmaxf(h, 0.f);                                   // ReLU (dropout = identity)
    float sc = gamma[lane] * rsqrtf(var[lane] + 1e-5f);  // BatchNorm (running stats)
    hbn = (h - mean[lane]) * sc + beta[lane];
  }
  hLDS[tid] = hbn;
  __syncthreads();
  if (node < N_NODES) {
    float acc = 0.f;
    const float* hp = &hLDS[grp * 64];
    #pragma unroll
    for (int k = 0; k < 64; ++k) acc += hp[k] * wLDS[k * 64 + lane];
    hw[node * 64 + lane] = acc;
    float d = deg[node];
    agg[node * 64 + lane] = acc / d;     // self-loop msg: hw * dis^2 = hw/deg
    if (lane == 0) dis[node] = rsqrtf(d);
  }
}

// ---------------- edge scatter: agg[dst] += hw[src] * dis[src]*dis[dst] ----------------
__global__ void k_scatter(const int* __restrict__ ei, const float* __restrict__ dis,
                          const float* __restrict__ hw, float* __restrict__ agg) {
  int lane = threadIdx.x & 63;
  int w = blockIdx.x * 4 + (threadIdx.x >> 6);
  int stride = gridDim.x * 4;
  for (int e = w; e < N_EDGES; e += stride) {
    int src = ei[e];
    int dst = ei[N_EDGES + e];
    float nrm = dis[src] * dis[dst];
    float v = hw[src * 64 + lane] * nrm;
    atomicAdd(&agg[dst * 64 + lane], v);
  }
}

// ---------------- bias + ReLU + mean-pool (sorted batch, run-accumulate) ----------------
__global__ void k_pool(const float* __restrict__ agg, const int* __restrict__ batch,
                       const float* __restrict__ bgcn,
                       float* __restrict__ gsum, float* __restrict__ gcnt) {
  int lane = threadIdx.x & 63;
  int w = blockIdx.x * 4 + (threadIdx.x >> 6);
  int n0 = w * 64;
  if (n0 >= N_NODES) return;
  int n1 = min(n0 + 64, N_NODES);
  int bv = (n0 + lane < N_NODES) ? batch[n0 + lane] : -1;  // coalesced, then shuffle
  float bias = bgcn[lane];
  float acc = 0.f;
  int cnt = 0;
  int cur = __shfl(bv, 0);
  for (int n = n0; n < n1; ++n) {
    int g = __shfl(bv, n - n0);
    if (g != cur) {
      atomicAdd(&gsum[cur * 64 + lane], acc);
      if (lane == 0) atomicAdd(&gcnt[cur], (float)cnt);
      acc = 0.f; cnt = 0; cur = g;
    }
    float v = fmaxf(agg[n * 64 + lane] + bias, 0.f);
    acc += v; cnt++;
  }
  atomicAdd(&gsum[cur * 64 + lane], acc);
  if (lane == 0) atomicAdd(&gcnt[cur], (float)cnt);
}

// ---------------- classifier: gm -> Linear+ReLU -> Linear ----------------
__global__ void k_cls(const float* __restrict__ gsum, const float* __restrict__ gcnt,
                      const float* __restrict__ W1, const float* __restrict__ b1,
                      const float* __restrict__ W2, const float* __restrict__ b2,
                      float* __restrict__ out) {
  __shared__ float gm[64];
  int j = threadIdx.x;
  int g = blockIdx.x;
  float denom = fmaxf(gcnt[g], 1.0f);
  gm[j] = gsum[g * 64 + j] / denom;
  __syncthreads();
  float hid = b1[j];
  #pragma unroll
  for (int k = 0; k < 64; ++k) hid += gm[k] * W1[k * 64 + j];
  hid = fmaxf(hid, 0.f);
  float o0 = hid * W2[j * 2 + 0];
  float o1 = hid * W2[j * 2 + 1];
  #pragma unroll
  for (int off = 32; off > 0; off >>= 1) {
    o0 += __shfl_down(o0, off);
    o1 += __shfl_down(o1, off);
  }
  if (j == 0) {
    out[g * 2 + 0] = o0 + b2[0];
    out[g * 2 + 1] = o1 + b2[1];
  }
}

extern "C" void kernel_launch(void* const* d_in, const int* in_sizes, int n_in,
                              void* d_out, int out_size, void* d_ws, size_t ws_size,
                              hipStream_t stream) {
  const float* x     = (const float*)d_in[0];
  const int*   ei    = (const int*)d_in[1];
  const int*   batch = (const int*)d_in[2];
  const float* Wenc  = (const float*)d_in[3];
  const float* benc  = (const float*)d_in[4];
  const float* gamma = (const float*)d_in[5];
  const float* beta  = (const float*)d_in[6];
  const float* mean  = (const float*)d_in[7];
  const float* var   = (const float*)d_in[8];
  const float* Wgcn  = (const float*)d_in[9];
  const float* bgcn  = (const float*)d_in[10];
  const float* W1    = (const float*)d_in[11];
  const float* b1    = (const float*)d_in[12];
  const float* W2    = (const float*)d_in[13];
  const float* b2    = (const float*)d_in[14];
  float* out = (float*)d_out;

  float* ws   = (float*)d_ws;
  float* hw   = ws;                              // N*64  (25.6 MB)
  float* agg  = hw  + (size_t)N_NODES * 64;      // N*64  (25.6 MB)
  float* deg  = agg + (size_t)N_NODES * 64;      // N
  float* dis  = deg + N_NODES;                   // N
  float* gsum = dis + N_NODES;                   // G*64
  float* gcnt = gsum + (size_t)N_GRAPHS * 64;    // G

  hipMemsetAsync(gsum, 0, (N_GRAPHS * 64 + N_GRAPHS) * sizeof(float), stream);
  k_init_deg<<<(N_NODES + 255) / 256, 256, 0, stream>>>(deg);
  k_deg<<<(N_EDGES + 255) / 256, 256, 0, stream>>>(ei, deg);
  k_enc<<<(N_NODES + 3) / 4, 256, 0, stream>>>(x, Wenc, benc, gamma, beta, mean, var,
                                               Wgcn, deg, hw, agg, dis);
  k_scatter<<<4096, 256, 0, stream>>>(ei, dis, hw, agg);
  int pool_waves = (N_NODES + 63) / 64;
  k_pool<<<(pool_waves + 3) / 4, 256, 0, stream>>>(agg, batch, bgcn, gsum, gcnt);
  k_cls<<<N_GRAPHS, 64, 0, stream>>>(gsum, gcnt, W1, b1, W2, b2, out);
}

// Round 2
// 427.140 us; speedup vs baseline: 1.1354x; 1.1354x over previous
//
#include <hip/hip_runtime.h>

#define N_NODES  100000
#define N_EDGES  1200000
#define N_GRAPHS 1024
#define NBLK ((N_NODES + 255) / 256)   // 391 scan blocks

// ---------------- degree histogram (int, dst row) ----------------
__global__ void k_hist(const int* __restrict__ ei, int* __restrict__ deg) {
  int e = blockIdx.x * 256 + threadIdx.x;
  if (e < N_EDGES) atomicAdd(&deg[ei[N_EDGES + e]], 1);
}

// ---------------- block partial sums for scan ----------------
__global__ void k_blocksum(const int* __restrict__ deg, int* __restrict__ part) {
  __shared__ int s[256];
  int tid = threadIdx.x;
  int i = blockIdx.x * 256 + tid;
  s[tid] = (i < N_NODES) ? deg[i] : 0;
  __syncthreads();
  for (int off = 128; off > 0; off >>= 1) {
    if (tid < off) s[tid] += s[tid + off];
    __syncthreads();
  }
  if (tid == 0) part[blockIdx.x] = s[0];
}

// ---------------- exclusive scan of 391 partials, one block ----------------
__global__ void k_scanpart(int* __restrict__ part) {
  __shared__ int s[512];
  int tid = threadIdx.x;
  int v = (tid < NBLK) ? part[tid] : 0;
  s[tid] = v;
  __syncthreads();
  for (int off = 1; off < 512; off <<= 1) {
    int t = (tid >= off) ? s[tid - off] : 0;
    __syncthreads();
    s[tid] += t;
    __syncthreads();
  }
  if (tid < NBLK) part[tid] = s[tid] - v;  // exclusive
}

// ------- per-node offsets (row_start, cursor), dis = rsqrt(deg+1), gcnt -------
__global__ void k_offsets(const int* __restrict__ deg, const int* __restrict__ part,
                          const int* __restrict__ batch,
                          int* __restrict__ row_start, int* __restrict__ cur,
                          float* __restrict__ dis, float* __restrict__ gcnt) {
  __shared__ int s[256];
  int tid = threadIdx.x;
  int i = blockIdx.x * 256 + tid;
  int v = (i < N_NODES) ? deg[i] : 0;
  s[tid] = v;
  __syncthreads();
  for (int off = 1; off < 256; off <<= 1) {
    int t = (tid >= off) ? s[tid - off] : 0;
    __syncthreads();
    s[tid] += t;
    __syncthreads();
  }
  if (i < N_NODES) {
    int rs = part[blockIdx.x] + s[tid] - v;  // exclusive within-block + base
    row_start[i] = rs;
    cur[i] = rs;
    dis[i] = rsqrtf((float)(v + 1));         // +1 self-loop
    atomicAdd(&gcnt[batch[i]], 1.0f);
  }
}

// ---------------- fill CSR: csr[cur[dst]++] = src ----------------
__global__ void k_fill(const int* __restrict__ ei, int* __restrict__ cur,
                       int* __restrict__ csr) {
  int e = blockIdx.x * 256 + threadIdx.x;
  if (e < N_EDGES) {
    int src = ei[e];
    int dst = ei[N_EDGES + e];
    int pos = atomicAdd(&cur[dst], 1);
    csr[pos] = src;
  }
}

// ------- fused encoder + BN + h@W_gcn -> hw (16 nodes/block) -------
__global__ void k_enc(const float* __restrict__ x,
                      const float* __restrict__ Wenc, const float* __restrict__ benc,
                      const float* __restrict__ gamma, const float* __restrict__ beta,
                      const float* __restrict__ mean,  const float* __restrict__ var,
                      const float* __restrict__ Wgcn,
                      float* __restrict__ hw) {
  __shared__ float wLDS[64 * 64];
  __shared__ float hLDS[256];
  int tid = threadIdx.x;
  for (int i = tid; i < 64 * 64; i += 256) wLDS[i] = Wgcn[i];
  int lane = tid & 63;
  int grp  = tid >> 6;
  float be = benc[lane];
  float sc = gamma[lane] * rsqrtf(var[lane] + 1e-5f);
  float mu = mean[lane], bt = beta[lane];
  float w0 = Wenc[lane], w1 = Wenc[64 + lane], w2 = Wenc[128 + lane], w3 = Wenc[192 + lane];
  for (int it = 0; it < 4; ++it) {
    int node = blockIdx.x * 16 + it * 4 + grp;
    float hbn = 0.f;
    if (node < N_NODES) {
      float4 xv = ((const float4*)x)[node];
      float h = be + xv.x * w0 + xv.y * w1 + xv.z * w2 + xv.w * w3;
      h = fmaxf(h, 0.f);                 // ReLU (dropout = identity)
      hbn = (h - mu) * sc + bt;          // BatchNorm (running stats)
    }
    __syncthreads();
    hLDS[tid] = hbn;
    __syncthreads();
    if (node < N_NODES) {
      float acc = 0.f;
      const float* hp = &hLDS[grp * 64];
      #pragma unroll
      for (int k = 0; k < 64; ++k) acc += hp[k] * wLDS[k * 64 + lane];
      hw[(size_t)node * 64 + lane] = acc;
    }
  }
}

// ------- gather per dst node + self-loop + bias + ReLU + pool-atomic -------
__global__ void k_gather(const int* __restrict__ row_start, const int* __restrict__ deg,
                         const int* __restrict__ csr, const float* __restrict__ dis,
                         const float* __restrict__ hw, const int* __restrict__ batch,
                         const float* __restrict__ bgcn, float* __restrict__ gsum) {
  int lane = threadIdx.x & 63;
  int n = blockIdx.x * 4 + (threadIdx.x >> 6);
  if (n >= N_NODES) return;
  int start = row_start[n];
  int cnt = deg[n];
  float dn = dis[n];
  float acc = hw[(size_t)n * 64 + lane] * (dn * dn);   // self-loop msg
  for (int c = 0; c < cnt; c += 64) {
    int e = c + lane;
    int sj = 0; float dj = 0.f;
    if (e < cnt) { sj = csr[start + e]; dj = dis[sj]; }
    int m = min(64, cnt - c);
    for (int j = 0; j < m; ++j) {
      int s = __shfl(sj, j);
      float d = __shfl(dj, j);
      acc += hw[(size_t)s * 64 + lane] * (d * dn);
    }
  }
  float v = fmaxf(acc + bgcn[lane], 0.f);              // + b_gcn, ReLU
  int g = batch[n];
  atomicAdd(&gsum[g * 64 + lane], v);                  // mean-pool numerator
}

// ---------------- classifier: gm -> Linear+ReLU -> Linear ----------------
__global__ void k_cls(const float* __restrict__ gsum, const float* __restrict__ gcnt,
                      const float* __restrict__ W1, const float* __restrict__ b1,
                      const float* __restrict__ W2, const float* __restrict__ b2,
                      float* __restrict__ out) {
  __shared__ float gm[64];
  int j = threadIdx.x;
  int g = blockIdx.x;
  float denom = fmaxf(gcnt[g], 1.0f);
  gm[j] = gsum[g * 64 + j] / denom;
  __syncthreads();
  float hid = b1[j];
  #pragma unroll
  for (int k = 0; k < 64; ++k) hid += gm[k] * W1[k * 64 + j];
  hid = fmaxf(hid, 0.f);
  float o0 = hid * W2[j * 2 + 0];
  float o1 = hid * W2[j * 2 + 1];
  #pragma unroll
  for (int off = 32; off > 0; off >>= 1) {
    o0 += __shfl_down(o0, off);
    o1 += __shfl_down(o1, off);
  }
  if (j == 0) {
    out[g * 2 + 0] = o0 + b2[0];
    out[g * 2 + 1] = o1 + b2[1];
  }
}

extern "C" void kernel_launch(void* const* d_in, const int* in_sizes, int n_in,
                              void* d_out, int out_size, void* d_ws, size_t ws_size,
                              hipStream_t stream) {
  const float* x     = (const float*)d_in[0];
  const int*   ei    = (const int*)d_in[1];
  const int*   batch = (const int*)d_in[2];
  const float* Wenc  = (const float*)d_in[3];
  const float* benc  = (const float*)d_in[4];
  const float* gamma = (const float*)d_in[5];
  const float* beta  = (const float*)d_in[6];
  const float* mean  = (const float*)d_in[7];
  const float* var   = (const float*)d_in[8];
  const float* Wgcn  = (const float*)d_in[9];
  const float* bgcn  = (const float*)d_in[10];
  const float* W1    = (const float*)d_in[11];
  const float* b1    = (const float*)d_in[12];
  const float* W2    = (const float*)d_in[13];
  const float* b2    = (const float*)d_in[14];
  float* out = (float*)d_out;

  char* ws = (char*)d_ws;
  int*   deg       = (int*)ws;                       ws += (size_t)N_NODES * 4;
  int*   row_start = (int*)ws;                       ws += (size_t)N_NODES * 4;
  int*   cur       = (int*)ws;                       ws += (size_t)N_NODES * 4;
  float* dis       = (float*)ws;                     ws += (size_t)N_NODES * 4;
  int*   csr       = (int*)ws;                       ws += (size_t)N_EDGES * 4;
  float* hw        = (float*)ws;                     ws += (size_t)N_NODES * 64 * 4;
  float* gsum      = (float*)ws;                     ws += (size_t)N_GRAPHS * 64 * 4;
  float* gcnt      = (float*)ws;                     ws += (size_t)N_GRAPHS * 4;
  int*   part      = (int*)ws;                       ws += 512 * 4;

  hipMemsetAsync(deg, 0, (size_t)N_NODES * 4, stream);
  hipMemsetAsync(gsum, 0, (size_t)(N_GRAPHS * 64 + N_GRAPHS) * 4, stream);

  k_hist<<<(N_EDGES + 255) / 256, 256, 0, stream>>>(ei, deg);
  k_blocksum<<<NBLK, 256, 0, stream>>>(deg, part);
  k_scanpart<<<1, 512, 0, stream>>>(part);
  k_offsets<<<NBLK, 256, 0, stream>>>(deg, part, batch, row_start, cur, dis, gcnt);
  k_fill<<<(N_EDGES + 255) / 256, 256, 0, stream>>>(ei, cur, csr);
  k_enc<<<(N_NODES + 15) / 16, 256, 0, stream>>>(x, Wenc, benc, gamma, beta, mean, var,
                                                 Wgcn, hw);
  k_gather<<<(N_NODES + 3) / 4, 256, 0, stream>>>(row_start, deg, csr, dis, hw, batch,
                                                  bgcn, gsum);
  k_cls<<<N_GRAPHS, 64, 0, stream>>>(gsum, gcnt, W1, b1, W2, b2, out);
}